// Round 4
// baseline (601.694 us; speedup 1.0000x reference)
//
#include <hip/hip_runtime.h>

typedef unsigned long long u64;
typedef unsigned int u32;
typedef unsigned short u16;

#define BATCH 2048
#define DIM   64
#define QSIZE 131072
#define HALFB 1024

#define BM 128
#define BN 128
#define NTILES (QSIZE / BN)              // 1024
#define NSPLIT 128                       // tiles per block = 8; grid 16x128 = 2048 blocks
#define ROWB   128                       // bytes per bf16 row (64 * 2)
#define PLANEG ((size_t)QSIZE * ROWB)    // 16 MiB per global plane (hi / lo)
#define PLANEL (BN * ROWB)               // 16 KiB per LDS plane

#define WS_SLOTS_BYTES 16384             // 2048 u64 argmax slots
#define WS_NEED (WS_SLOTS_BYTES + 2 * PLANEG)

typedef __attribute__((ext_vector_type(8)))  short short8;
typedef __attribute__((ext_vector_type(4)))  short short4v;
typedef __attribute__((ext_vector_type(16))) float f32x16;

__device__ __forceinline__ u16 bf16rn(float f) {
  u32 b = __float_as_uint(f);
  return (u16)((b + 0x7FFFu + ((b >> 16) & 1u)) >> 16);
}
__device__ __forceinline__ float bf16tof(u16 h) {
  return __uint_as_float(((u32)h) << 16);
}

__device__ __forceinline__ void gload_lds16(const void* g, void* l) {
  __builtin_amdgcn_global_load_lds(
      (__attribute__((address_space(1))) void*)(g),
      (__attribute__((address_space(3))) void*)(l),
      16, 0, 0);
}

__device__ __forceinline__ void conv_write_qc(int i, float4 v, char* qc) {
  int row = i >> 4;
  int c4  = i & 15;
  float vv[4] = {v.x, v.y, v.z, v.w};
  short4v hv, lv;
#pragma unroll
  for (int k = 0; k < 4; ++k) {
    u16 hb = bf16rn(vv[k]);
    u16 lb = bf16rn(vv[k] - bf16tof(hb));
    hv[k] = (short)hb;
    lv[k] = (short)lb;
  }
  int chunk = c4 >> 1, half = c4 & 1;
  int phys  = chunk ^ (row & 7);              // XOR swizzle -> bank-uniform LDS staging
  size_t off = (size_t)row * ROWB + phys * 16 + half * 8;
  *(short4v*)(qc + off)          = hv;
  *(short4v*)(qc + PLANEG + off) = lv;
}

// Main path: convert q -> bf16 hi/lo planes in d_ws, AND produce the final
// new_queue output in the same pass (q row already in registers). Zeroes ws slots.
__global__ void preconv_merge_kernel(const float* __restrict__ q,
                                     const float* __restrict__ x,
                                     const int* __restrict__ ptr_in,
                                     char* __restrict__ qc,
                                     float* __restrict__ newq,
                                     u64* __restrict__ ws)
{
  int i = blockIdx.x * 256 + threadIdx.x;   // float4 id, QSIZE*16 total
  if (i < BATCH) ws[i] = 0;
  float4 v = ((const float4*)q)[i];
  conv_write_qc(i, v, qc);
  int row = i >> 4;
  int c4  = i & 15;
  int ptr = *ptr_in;
  u32 off = (u32)(row - ptr) & (QSIZE - 1);
  float4 w = (off < HALFB) ? ((const float4*)x)[off * 16 + c4] : v;
  ((float4*)newq)[i] = w;
}

// Fallback (ws too small): convert only, qc lives in the newq region.
__global__ void preconv_kernel(const float* __restrict__ q, char* __restrict__ qc,
                               u64* __restrict__ ws)
{
  int i = blockIdx.x * 256 + threadIdx.x;
  if (i < BATCH) ws[i] = 0;
  float4 v = ((const float4*)q)[i];
  conv_write_qc(i, v, qc);
}

// sim = x . q^T via 3-pass bf16 hi/lo MFMA, fused row-argmax.
// 128x128 tile/block, 32 KB LDS -> 4 blocks/CU; 4 waves 2x2; A persistent in regs;
// B staged via global_load_lds (16B) from the pre-swizzled bf16 planes.
__global__ __launch_bounds__(256, 4) void sim_argmax_kernel(
    const float* __restrict__ x, const char* __restrict__ qc,
    u64* __restrict__ ws)
{
  __shared__ char smem[2 * PLANEL];   // 32 KB (staging; aliased by reduce table)

  const int tid  = threadIdx.x;
  const int lane = tid & 63;
  const int wave = tid >> 6;
  const int wm   = wave & 1;    // m-half
  const int wn   = wave >> 1;   // n-half
  const int l31  = lane & 31;
  const int lh   = lane >> 5;
  const int mblk = blockIdx.x * BM;

  // persistent A fragments: A[m=l31][k=lh*8+j]
  short8 ah[2][4], al[2][4];
#pragma unroll
  for (int ms = 0; ms < 2; ++ms) {
    const float* xr = x + (size_t)(mblk + wm * 64 + ms * 32 + l31) * DIM;
#pragma unroll
    for (int kt = 0; kt < 4; ++kt) {
      const float* p = xr + kt * 16 + lh * 8;
      float4 v0 = *(const float4*)(p);
      float4 v1 = *(const float4*)(p + 4);
      float vv[8] = {v0.x, v0.y, v0.z, v0.w, v1.x, v1.y, v1.z, v1.w};
      short8 h, l;
#pragma unroll
      for (int i = 0; i < 8; ++i) {
        u16 hb = bf16rn(vv[i]);
        u16 lb = bf16rn(vv[i] - bf16tof(hb));
        h[i] = (short)hb;
        l[i] = (short)lb;
      }
      ah[ms][kt] = h;
      al[ms][kt] = l;
    }
  }

  float best[2][16];
  u32   bidx[2][16];
#pragma unroll
  for (int ms = 0; ms < 2; ++ms)
#pragma unroll
    for (int r = 0; r < 16; ++r) { best[ms][r] = -3.0e38f; bidx[ms][r] = 0; }

  char* lb = smem + wave * 1024;   // wave-uniform LDS staging base

  for (int it = 0; it < NTILES / NSPLIT; ++it) {
    const int nt = blockIdx.y + it * NSPLIT;
    const size_t tileoff = (size_t)nt * PLANEL;
    __syncthreads();   // prior tile's fragment reads complete
    const char* shi = qc + tileoff + wave * 1024 + lane * 16;
    const char* slo = shi + PLANEG;
#pragma unroll
    for (int p = 0; p < 4; ++p) gload_lds16(shi + p * 4096, lb + p * 4096);
#pragma unroll
    for (int p = 0; p < 4; ++p) gload_lds16(slo + p * 4096, lb + PLANEL + p * 4096);
    __syncthreads();   // vmcnt drained before barrier -> DMA complete

#pragma unroll
    for (int ns = 0; ns < 2; ++ns) {
      const int brow = wn * 64 + ns * 32 + l31;
      const int sw   = brow & 7;
      short8 bh[4], bl[4];
#pragma unroll
      for (int kt = 0; kt < 4; ++kt) {
        int off = brow * ROWB + (((kt * 2 + lh) ^ sw) << 4);
        bh[kt] = *(const short8*)(smem + off);
        bl[kt] = *(const short8*)(smem + PLANEL + off);
      }
      const u32 col = (u32)(nt * BN + wn * 64 + ns * 32 + l31);

#pragma unroll
      for (int ms = 0; ms < 2; ++ms) {
        f32x16 acc;
#pragma unroll
        for (int i = 0; i < 16; ++i) acc[i] = 0.0f;
#pragma unroll
        for (int kt = 0; kt < 4; ++kt) {
          acc = __builtin_amdgcn_mfma_f32_32x32x16_bf16(ah[ms][kt], bh[kt], acc, 0, 0, 0);
          acc = __builtin_amdgcn_mfma_f32_32x32x16_bf16(al[ms][kt], bh[kt], acc, 0, 0, 0);
          acc = __builtin_amdgcn_mfma_f32_32x32x16_bf16(ah[ms][kt], bl[kt], acc, 0, 0, 0);
        }
        // col scans ascending (it asc, ns asc); strict '>' keeps smallest index.
#pragma unroll
        for (int r = 0; r < 16; ++r) {
          if (acc[r] > best[ms][r]) { best[ms][r] = acc[r]; bidx[ms][r] = col; }
        }
      }
    }
  }

  // block reduce: table[row 0..127][l31 0..31], two wn phases, then 128-thread scan
  __syncthreads();
  u64* table = (u64*)smem;   // 32 KB, aliases staging
  if (wn == 0) {
#pragma unroll
    for (int ms = 0; ms < 2; ++ms)
#pragma unroll
      for (int r = 0; r < 16; ++r) {
        int row = wm * 64 + ms * 32 + (r & 3) + 8 * (r >> 2) + 4 * lh;
        u32 fb = __float_as_uint(best[ms][r]);
        fb = (fb & 0x80000000u) ? ~fb : (fb | 0x80000000u);
        table[row * 32 + l31] = ((u64)fb << 32) | (u32)(~bidx[ms][r]);
      }
  }
  __syncthreads();
  if (wn == 1) {
#pragma unroll
    for (int ms = 0; ms < 2; ++ms)
#pragma unroll
      for (int r = 0; r < 16; ++r) {
        int row = wm * 64 + ms * 32 + (r & 3) + 8 * (r >> 2) + 4 * lh;
        u32 fb = __float_as_uint(best[ms][r]);
        fb = (fb & 0x80000000u) ? ~fb : (fb | 0x80000000u);
        u64 pk = ((u64)fb << 32) | (u32)(~bidx[ms][r]);
        u64* slot = &table[row * 32 + l31];
        if (pk > *slot) *slot = pk;   // unique writer per slot in this phase
      }
  }
  __syncthreads();
  if (tid < BM) {
    u64 mx = 0;
    for (int j = 0; j < 32; ++j) {
      u64 v = table[tid * 32 + j];
      mx = (v > mx) ? v : mx;
    }
    atomicMax(&ws[mblk + tid], mx);
  }
}

// Main-path tail: nn gather + ptr only (newq already produced by preconv_merge).
__global__ void gather_kernel(const float* __restrict__ q,
                              const u64* __restrict__ ws,
                              const int* __restrict__ ptr_in,
                              float* __restrict__ nn,
                              float* __restrict__ nptr)
{
  int t = blockIdx.x * 256 + threadIdx.x;
  int b = t >> 6;
  int d = t & 63;
  u32 qidx = ~(u32)(ws[b]);
  nn[t] = q[(size_t)qidx * DIM + d];
  if (t == 0) *nptr = (float)(((*ptr_in) + HALFB) & (QSIZE - 1));
}

// Fallback tail: copy-with-substitution + gather + ptr (round-3 structure).
__global__ void finish_kernel(const float* __restrict__ x, const float* __restrict__ q,
                              const int* __restrict__ ptr_in, const u64* __restrict__ ws,
                              float* __restrict__ nn, float* __restrict__ newq,
                              float* __restrict__ nptr)
{
  int bid = blockIdx.x;
  if (bid < 8192) {
    int i = bid * 256 + threadIdx.x;
    int r = i >> 4;
    int c = i & 15;
    int ptr = *ptr_in;
    u32 off = (u32)(r - ptr) & (QSIZE - 1);
    float4 v = (off < HALFB) ? ((const float4*)x)[off * 16 + c]
                             : ((const float4*)q)[i];
    ((float4*)newq)[i] = v;
  } else {
    int t = (bid - 8192) * 256 + threadIdx.x;
    int b = t >> 6;
    int d = t & 63;
    u32 qidx = ~(u32)(ws[b]);
    nn[t] = q[(size_t)qidx * DIM + d];
    if (t == 0) *nptr = (float)(((*ptr_in) + HALFB) & (QSIZE - 1));
  }
}

extern "C" void kernel_launch(void* const* d_in, const int* in_sizes, int n_in,
                              void* d_out, int out_size, void* d_ws, size_t ws_size,
                              hipStream_t stream)
{
  const float* x   = (const float*)d_in[0];
  const float* qx  = (const float*)d_in[1];
  const int*   ptr = (const int*)d_in[2];

  float* out  = (float*)d_out;
  float* nn   = out;
  float* newq = out + BATCH * DIM;
  float* nptr = out + BATCH * DIM + (size_t)QSIZE * DIM;

  u64* ws = (u64*)d_ws;   // [0,16K): argmax slots; [16K,16K+32M): qc (main path)

  dim3 grid(BATCH / BM, NSPLIT);

  if (ws_size >= WS_NEED) {
    char* qc = (char*)d_ws + WS_SLOTS_BYTES;
    preconv_merge_kernel<<<QSIZE * 16 / 256, 256, 0, stream>>>(qx, x, ptr, qc, newq, ws);
    sim_argmax_kernel<<<grid, 256, 0, stream>>>(x, qc, ws);
    gather_kernel<<<(BATCH * DIM) / 256, 256, 0, stream>>>(qx, ws, ptr, nn, nptr);
  } else {
    char* qc = (char*)newq;   // scratch inside the newq slot, overwritten by finish
    preconv_kernel<<<QSIZE * 16 / 256, 256, 0, stream>>>(qx, qc, ws);
    sim_argmax_kernel<<<grid, 256, 0, stream>>>(x, qc, ws);
    finish_kernel<<<8192 + (BATCH * DIM) / 256, 256, 0, stream>>>(
        x, qx, ptr, ws, nn, newq, nptr);
  }
}

// Round 5
// 270.663 us; speedup vs baseline: 2.2230x; 2.2230x over previous
//
#include <hip/hip_runtime.h>

typedef unsigned long long u64;
typedef unsigned int u32;
typedef unsigned short u16;

#define BATCH 2048
#define DIM   64
#define QSIZE 131072
#define HALFB 1024

#define XCP (BATCH * DIM * 2)   // 256 KB: bytes per x bf16 plane (hi / lo)

typedef __attribute__((ext_vector_type(8)))  short short8;
typedef __attribute__((ext_vector_type(4)))  short short4v;
typedef __attribute__((ext_vector_type(16))) float f32x16;

__device__ __forceinline__ u16 bf16rn(float f) {
  u32 b = __float_as_uint(f);
  return (u16)((b + 0x7FFFu + ((b >> 16) & 1u)) >> 16);
}
__device__ __forceinline__ float bf16tof(u16 h) {
  return __uint_as_float(((u32)h) << 16);
}

// x fp32 -> bf16 hi/lo planes (contiguous, row-major); also zero the 2048 argmax slots.
__global__ void xconv_kernel(const float* __restrict__ x, char* __restrict__ xc,
                             u64* __restrict__ ws)
{
  int i = blockIdx.x * 256 + threadIdx.x;   // float4 id, BATCH*DIM/4 = 32768 total
  if (i < BATCH) ws[i] = 0;
  float4 v = ((const float4*)x)[i];
  float vv[4] = {v.x, v.y, v.z, v.w};
  short4v hv, lv;
#pragma unroll
  for (int k = 0; k < 4; ++k) {
    u16 hb = bf16rn(vv[k]);
    u16 lb = bf16rn(vv[k] - bf16tof(hb));
    hv[k] = (short)hb;
    lv[k] = (short)lb;
  }
  *(short4v*)(xc + (size_t)i * 8)       = hv;
  *(short4v*)(xc + XCP + (size_t)i * 8) = lv;
}

// sim = x . q^T via 3-pass bf16 hi/lo MFMA with SWAPPED roles: A = q (persistent
// in registers, 64 cols/wave for the whole kernel), B = x (bf16 planes, L2-hot,
// double-buffered register loads). No LDS, no barriers. C layout: col(lane&31) =
// x-row, row(reg) = q-col -> per-lane argmax fold + one atomicMax per x-row.
__global__ __launch_bounds__(256) void sim_kernel(
    const float* __restrict__ q, const char* __restrict__ xc,
    u64* __restrict__ ws)
{
  const int tid  = threadIdx.x;
  const int lane = tid & 63;
  const int wave = tid >> 6;
  const int l31  = lane & 31;
  const int lh   = lane >> 5;

  const int W = blockIdx.x * 4 + wave;    // global wave id, 0..2047
  const int colbase = W * 64;             // this wave's 64 q-columns

  // ---- persistent A fragments from q (fp32 -> hi/lo in-register), read once ----
  short8 ah[2][4], al[2][4];
#pragma unroll
  for (int ns = 0; ns < 2; ++ns) {
    const float* qr = q + (size_t)(colbase + ns * 32 + l31) * DIM + lh * 8;
#pragma unroll
    for (int kt = 0; kt < 4; ++kt) {
      float4 v0 = *(const float4*)(qr + kt * 16);
      float4 v1 = *(const float4*)(qr + kt * 16 + 4);
      float vv[8] = {v0.x, v0.y, v0.z, v0.w, v1.x, v1.y, v1.z, v1.w};
      short8 h, l;
#pragma unroll
      for (int i = 0; i < 8; ++i) {
        u16 hb = bf16rn(vv[i]);
        u16 lb = bf16rn(vv[i] - bf16tof(hb));
        h[i] = (short)hb;
        l[i] = (short)lb;
      }
      ah[ns][kt] = h;
      al[ns][kt] = l;
    }
  }

  // per-lane byte offset into an x plane for (row = m0 + l31, k-seg = kt*16 + lh*8)
  const int lanoff = l31 * 128 + lh * 16;
  const int colb4  = colbase + 4 * lh;

  short8 b0h[4], b0l[4], b1h[4], b1l[4];

#define LOADB(BH, BL, M0)                                                   \
  {                                                                         \
    const char* ph = xc + (size_t)(M0) * 128 + lanoff;                      \
    const char* pl = ph + XCP;                                              \
    _Pragma("unroll")                                                       \
    for (int kt = 0; kt < 4; ++kt) {                                        \
      BH[kt] = *(const short8*)(ph + kt * 32);                              \
      BL[kt] = *(const short8*)(pl + kt * 32);                              \
    }                                                                       \
  }

#define COMPUTE(BH, BL, M0)                                                 \
  {                                                                         \
    float bv = -3.0e38f;                                                    \
    u32   bc = 0;                                                           \
    _Pragma("unroll")                                                       \
    for (int ns = 0; ns < 2; ++ns) {                                        \
      f32x16 acc;                                                           \
      _Pragma("unroll")                                                     \
      for (int i = 0; i < 16; ++i) acc[i] = 0.0f;                           \
      _Pragma("unroll")                                                     \
      for (int kt = 0; kt < 4; ++kt) {                                      \
        acc = __builtin_amdgcn_mfma_f32_32x32x16_bf16(ah[ns][kt], BH[kt], acc, 0, 0, 0); \
        acc = __builtin_amdgcn_mfma_f32_32x32x16_bf16(al[ns][kt], BH[kt], acc, 0, 0, 0); \
        acc = __builtin_amdgcn_mfma_f32_32x32x16_bf16(ah[ns][kt], BL[kt], acc, 0, 0, 0); \
      }                                                                     \
      /* ascending q-col within lane; strict '>' -> smallest col on ties */ \
      _Pragma("unroll")                                                     \
      for (int r = 0; r < 16; ++r) {                                        \
        u32 c = (u32)(colb4 + ns * 32 + (r & 3) + 8 * (r >> 2));            \
        if (acc[r] > bv) { bv = acc[r]; bc = c; }                           \
      }                                                                     \
    }                                                                       \
    u32 fb = __float_as_uint(bv);                                           \
    fb = (fb & 0x80000000u) ? ~fb : (fb | 0x80000000u);                     \
    u64 key = ((u64)fb << 32) | (u32)(~bc);                                 \
    u64 oth = __shfl_xor((unsigned long long)key, 32);                      \
    key = (oth > key) ? oth : key;   /* tie -> larger ~col = smaller col */ \
    if (lh == 0) atomicMax(&ws[(M0) + l31], key);                           \
  }

  LOADB(b0h, b0l, 0)
  for (int m0 = 0; m0 < BATCH; m0 += 64) {
    int n1 = m0 + 32;
    LOADB(b1h, b1l, n1)
    COMPUTE(b0h, b0l, m0)
    int n2 = (m0 + 64 < BATCH) ? m0 + 64 : 0;
    LOADB(b0h, b0l, n2)
    COMPUTE(b1h, b1l, n1)
  }
#undef LOADB
#undef COMPUTE
}

// new_queue: copy queue, substituting rows [ptr, ptr+1024) mod SIZE from x (R1-proven).
__global__ void copy_update_kernel(const float* __restrict__ x,
                                   const float* __restrict__ q,
                                   const int* __restrict__ ptr_in,
                                   float* __restrict__ newq)
{
  int i = blockIdx.x * 256 + threadIdx.x;   // float4 index
  int r = i >> 4;
  int c = i & 15;
  int ptr = *ptr_in;
  u32 off = (u32)(r - ptr) & (QSIZE - 1);
  float4 v = (off < HALFB) ? ((const float4*)x)[off * 16 + c]
                           : ((const float4*)q)[i];
  ((float4*)newq)[i] = v;
}

__global__ void gather_kernel(const float* __restrict__ q,
                              const u64* __restrict__ ws,
                              const int* __restrict__ ptr_in,
                              float* __restrict__ nn,
                              float* __restrict__ nptr)
{
  int t = blockIdx.x * 256 + threadIdx.x;
  int b = t >> 6;
  int d = t & 63;
  u32 qidx = ~(u32)(ws[b]);
  nn[t] = q[(size_t)qidx * DIM + d];
  if (t == 0) *nptr = (float)(((*ptr_in) + HALFB) & (QSIZE - 1));
}

extern "C" void kernel_launch(void* const* d_in, const int* in_sizes, int n_in,
                              void* d_out, int out_size, void* d_ws, size_t ws_size,
                              hipStream_t stream)
{
  const float* x   = (const float*)d_in[0];
  const float* qx  = (const float*)d_in[1];
  const int*   ptr = (const int*)d_in[2];

  float* out  = (float*)d_out;
  float* nn   = out;
  float* newq = out + BATCH * DIM;
  float* nptr = out + BATCH * DIM + (size_t)QSIZE * DIM;

  // d_ws layout: [0, 16K) argmax slots; [16K, 16K + 512K) x bf16 hi/lo planes
  u64*  ws = (u64*)d_ws;
  char* xc = (char*)d_ws + 16384;

  xconv_kernel<<<BATCH * DIM / 4 / 256, 256, 0, stream>>>(x, xc, ws);

  sim_kernel<<<512, 256, 0, stream>>>(qx, xc, ws);

  copy_update_kernel<<<QSIZE * DIM / 4 / 256, 256, 0, stream>>>(x, qx, ptr, newq);

  gather_kernel<<<(BATCH * DIM) / 256, 256, 0, stream>>>(qx, ws, ptr, nn, nptr);
}

// Round 6
// 226.895 us; speedup vs baseline: 2.6519x; 1.1929x over previous
//
#include <hip/hip_runtime.h>

typedef unsigned long long u64;
typedef unsigned int u32;
typedef unsigned short u16;

#define BATCH 2048
#define DIM   64
#define QSIZE 131072
#define HALFB 1024

#define XCP (BATCH * DIM * 2)      // 256 KB: bytes per x bf16 plane (hi / lo)
#define NBLK 512                   // sim blocks (4 waves each, 64 q-cols per wave)
#define WS_SLOTS 16384             // 2048 u64 argmax slots
#define WS_XC    (2 * XCP)         // 512 KB bf16 planes
#define WS_CAND  ((size_t)NBLK * BATCH * 8)   // 8 MB candidate buffer
#define WS_NEED  (WS_SLOTS + WS_XC + WS_CAND)

typedef __attribute__((ext_vector_type(8)))  short short8;
typedef __attribute__((ext_vector_type(4)))  short short4v;
typedef __attribute__((ext_vector_type(16))) float f32x16;

__device__ __forceinline__ u16 bf16rn(float f) {
  u32 b = __float_as_uint(f);
  return (u16)((b + 0x7FFFu + ((b >> 16) & 1u)) >> 16);
}
__device__ __forceinline__ float bf16tof(u16 h) {
  return __uint_as_float(((u32)h) << 16);
}

// x fp32 -> bf16 hi/lo planes (contiguous, row-major); also zero the 2048 argmax slots.
__global__ void xconv_kernel(const float* __restrict__ x, char* __restrict__ xc,
                             u64* __restrict__ ws)
{
  int i = blockIdx.x * 256 + threadIdx.x;   // float4 id, BATCH*DIM/4 = 32768 total
  if (i < BATCH) ws[i] = 0;
  float4 v = ((const float4*)x)[i];
  float vv[4] = {v.x, v.y, v.z, v.w};
  short4v hv, lv;
#pragma unroll
  for (int k = 0; k < 4; ++k) {
    u16 hb = bf16rn(vv[k]);
    u16 lb = bf16rn(vv[k] - bf16tof(hb));
    hv[k] = (short)hb;
    lv[k] = (short)lb;
  }
  *(short4v*)(xc + (size_t)i * 8)       = hv;
  *(short4v*)(xc + XCP + (size_t)i * 8) = lv;
}

// sim = x . q^T via 3-pass bf16 hi/lo MFMA, swapped roles: A = q (persistent in
// registers, 64 cols/wave), B = x (bf16 planes, L2-hot, double-buffered register
// loads). Candidates reduced through a per-block LDS table (ds-atomics), dumped
// with plain coalesced stores to cand[block][row] -> no global atomic contention.
// Fallback (cand == nullptr): direct global atomicMax into ws.
__global__ __launch_bounds__(256) void sim_kernel(
    const float* __restrict__ q, const char* __restrict__ xc,
    u64* __restrict__ ws, u64* __restrict__ cand)
{
  __shared__ u64 table[BATCH];   // 16 KB per-block candidate table

  const int tid  = threadIdx.x;
  const int lane = tid & 63;
  const int wave = tid >> 6;
  const int l31  = lane & 31;
  const int lh   = lane >> 5;

  const int W = blockIdx.x * 4 + wave;    // global wave id, 0..2047
  const int colbase = W * 64;             // this wave's 64 q-columns

  if (cand) {
#pragma unroll
    for (int k = 0; k < 8; ++k) table[tid + k * 256] = 0;
    __syncthreads();
  }

  // ---- persistent A fragments from q (fp32 -> hi/lo in-register), read once ----
  short8 ah[2][4], al[2][4];
#pragma unroll
  for (int ns = 0; ns < 2; ++ns) {
    const float* qr = q + (size_t)(colbase + ns * 32 + l31) * DIM + lh * 8;
#pragma unroll
    for (int kt = 0; kt < 4; ++kt) {
      float4 v0 = *(const float4*)(qr + kt * 16);
      float4 v1 = *(const float4*)(qr + kt * 16 + 4);
      float vv[8] = {v0.x, v0.y, v0.z, v0.w, v1.x, v1.y, v1.z, v1.w};
      short8 h, l;
#pragma unroll
      for (int i = 0; i < 8; ++i) {
        u16 hb = bf16rn(vv[i]);
        u16 lb = bf16rn(vv[i] - bf16tof(hb));
        h[i] = (short)hb;
        l[i] = (short)lb;
      }
      ah[ns][kt] = h;
      al[ns][kt] = l;
    }
  }

  // per-lane byte offset into an x plane for (row = m0 + l31, k-seg = kt*16 + lh*8)
  const int lanoff = l31 * 128 + lh * 16;
  const int colb4  = colbase + 4 * lh;

  short8 b0h[4], b0l[4], b1h[4], b1l[4];

#define LOADB(BH, BL, M0)                                                   \
  {                                                                         \
    const char* ph = xc + (size_t)(M0) * 128 + lanoff;                      \
    const char* pl = ph + XCP;                                              \
    _Pragma("unroll")                                                       \
    for (int kt = 0; kt < 4; ++kt) {                                        \
      BH[kt] = *(const short8*)(ph + kt * 32);                              \
      BL[kt] = *(const short8*)(pl + kt * 32);                              \
    }                                                                       \
  }

#define COMPUTE(BH, BL, M0)                                                 \
  {                                                                         \
    float bv = -3.0e38f;                                                    \
    u32   bc = 0;                                                           \
    _Pragma("unroll")                                                       \
    for (int ns = 0; ns < 2; ++ns) {                                        \
      f32x16 acc;                                                           \
      _Pragma("unroll")                                                     \
      for (int i = 0; i < 16; ++i) acc[i] = 0.0f;                           \
      _Pragma("unroll")                                                     \
      for (int kt = 0; kt < 4; ++kt) {                                      \
        acc = __builtin_amdgcn_mfma_f32_32x32x16_bf16(ah[ns][kt], BH[kt], acc, 0, 0, 0); \
        acc = __builtin_amdgcn_mfma_f32_32x32x16_bf16(al[ns][kt], BH[kt], acc, 0, 0, 0); \
        acc = __builtin_amdgcn_mfma_f32_32x32x16_bf16(ah[ns][kt], BL[kt], acc, 0, 0, 0); \
      }                                                                     \
      /* ascending q-col within lane; strict '>' -> smallest col on ties */ \
      _Pragma("unroll")                                                     \
      for (int r = 0; r < 16; ++r) {                                        \
        u32 c = (u32)(colb4 + ns * 32 + (r & 3) + 8 * (r >> 2));            \
        if (acc[r] > bv) { bv = acc[r]; bc = c; }                           \
      }                                                                     \
    }                                                                       \
    u32 fb = __float_as_uint(bv);                                           \
    fb = (fb & 0x80000000u) ? ~fb : (fb | 0x80000000u);                     \
    u64 key = ((u64)fb << 32) | (u32)(~bc);                                 \
    if (cand) atomicMax(&table[(M0) + l31], key);                           \
    else      atomicMax(&ws[(M0) + l31], key);                              \
  }

  LOADB(b0h, b0l, 0)
  for (int m0 = 0; m0 < BATCH; m0 += 64) {
    int n1 = m0 + 32;
    LOADB(b1h, b1l, n1)
    COMPUTE(b0h, b0l, m0)
    int n2 = (m0 + 64 < BATCH) ? m0 + 64 : 0;
    LOADB(b0h, b0l, n2)
    COMPUTE(b1h, b1l, n1)
  }
#undef LOADB
#undef COMPUTE

  if (cand) {
    __syncthreads();
    u64* dst = cand + (size_t)blockIdx.x * BATCH;
#pragma unroll
    for (int k = 0; k < 8; ++k) dst[tid + k * 256] = table[tid + k * 256];
  }
}

// Fused: new_queue copy-with-substitution (blocks 0..8191) + candidate reduce
// (blocks 8192..8319: 512 waves, wave = 64 rows x 32-block chunk, coalesced).
__global__ void finish_kernel(const float* __restrict__ x, const float* __restrict__ q,
                              const int* __restrict__ ptr_in,
                              const u64* __restrict__ cand,
                              u64* __restrict__ ws, float* __restrict__ newq)
{
  int bid = blockIdx.x;
  if (bid < 8192) {
    int i = bid * 256 + threadIdx.x;   // float4 index
    int r = i >> 4;
    int c = i & 15;
    int ptr = *ptr_in;
    u32 off = (u32)(r - ptr) & (QSIZE - 1);
    float4 v = (off < HALFB) ? ((const float4*)x)[off * 16 + c]
                             : ((const float4*)q)[i];
    ((float4*)newq)[i] = v;
  } else if (cand) {
    int w    = (bid - 8192) * 4 + (threadIdx.x >> 6);  // 0..511
    int lane = threadIdx.x & 63;
    int row  = (w & 31) * 64 + lane;                   // 32 row-groups of 64
    int b0   = (w >> 5) * 32;                          // 16 chunks of 32 blocks
    u64 mx = 0;
#pragma unroll 8
    for (int b = b0; b < b0 + 32; ++b) {
      u64 v = cand[(size_t)b * BATCH + row];
      mx = (v > mx) ? v : mx;
    }
    atomicMax(&ws[row], mx);   // 16 atomics per slot, spread wide -> no contention
  }
}

__global__ void gather_kernel(const float* __restrict__ q,
                              const u64* __restrict__ ws,
                              const int* __restrict__ ptr_in,
                              float* __restrict__ nn,
                              float* __restrict__ nptr)
{
  int t = blockIdx.x * 256 + threadIdx.x;
  int b = t >> 6;
  int d = t & 63;
  u32 qidx = ~(u32)(ws[b]);
  nn[t] = q[(size_t)qidx * DIM + d];
  if (t == 0) *nptr = (float)(((*ptr_in) + HALFB) & (QSIZE - 1));
}

extern "C" void kernel_launch(void* const* d_in, const int* in_sizes, int n_in,
                              void* d_out, int out_size, void* d_ws, size_t ws_size,
                              hipStream_t stream)
{
  const float* x   = (const float*)d_in[0];
  const float* qx  = (const float*)d_in[1];
  const int*   ptr = (const int*)d_in[2];

  float* out  = (float*)d_out;
  float* nn   = out;
  float* newq = out + BATCH * DIM;
  float* nptr = out + BATCH * DIM + (size_t)QSIZE * DIM;

  // d_ws: [0,16K) argmax slots | [16K,528K) x bf16 planes | [528K,528K+8M) cand
  u64*  ws   = (u64*)d_ws;
  char* xc   = (char*)d_ws + WS_SLOTS;
  u64*  cand = (ws_size >= WS_NEED) ? (u64*)((char*)d_ws + WS_SLOTS + WS_XC) : nullptr;

  xconv_kernel<<<BATCH * DIM / 4 / 256, 256, 0, stream>>>(x, xc, ws);

  sim_kernel<<<NBLK, 256, 0, stream>>>(qx, xc, ws, cand);

  finish_kernel<<<8192 + (cand ? 128 : 0), 256, 0, stream>>>(
      x, qx, ptr, cand, ws, newq);

  gather_kernel<<<(BATCH * DIM) / 256, 256, 0, stream>>>(qx, ws, ptr, nn, nptr);
}